// Round 3
// baseline (300.983 us; speedup 1.0000x reference)
//
#include <hip/hip_runtime.h>
#include <cstdint>

#define TICKS   1000
#define KH      7
#define KW      7
#define NTAPS   49
#define OUT_CH  128

#define BUF_ELEMS   (NTAPS * TICKS)      // 49000 floats at ws[0]
#define P_OFF_B     196608               // byte offset of P[t*128+c] (128000 floats)
#define P_ELEMS     (OUT_CH * TICKS)
#define BINS_OFF_B  708608               // byte offset of class bins

// x-classes: x<6 -> x exactly; x>=6 -> 6 + (x-6)%stride.  Validity of tap kx for
// class cx is (cx>=kx) && ((cx-kx)%stride==0) — exact for x<6; for x>=6, cx>=6>=kx
// always, and (x-kx) ≡ (cx-kx) (mod stride) since x ≡ cx (mod stride).
// For any stride, cx ≤ 127 (COORD_MAX=128), so the nc cap at 128 is lossless.
static __device__ __forceinline__ int num_classes(int stride) {
    int n = (KW - 1) + stride;
    return n > 128 ? 128 : n;
}

static __device__ __forceinline__ bool use_class(int stride, unsigned long long ws_size) {
    if (stride < 1) return false;
    long long nc = num_classes(stride);
    long long bytes = (long long)TICKS * nc * nc * 4;
    return (long long)BINS_OFF_B + bytes <= (long long)ws_size;
}

__global__ void zero_kernel(float* ws, const int* __restrict__ stride_p,
                            unsigned long long ws_size) {
    int stride = *stride_p;
    long long nbins = 0;
    if (use_class(stride, ws_size)) {
        long long nc = num_classes(stride);
        nbins = (long long)TICKS * nc * nc;
    }
    float* bins = (float*)((char*)ws + BINS_OFF_B);
    long long gid = (long long)blockIdx.x * blockDim.x + threadIdx.x;
    long long gsz = (long long)gridDim.x * blockDim.x;
    for (long long i = gid; i < BUF_ELEMS; i += gsz) ws[i] = 0.0f;
    for (long long i = gid; i < nbins; i += gsz) bins[i] = 0.0f;
}

__global__ void scatter_kernel(const int* __restrict__ ticks, const int* __restrict__ xs,
                               const int* __restrict__ ys, const float* __restrict__ vals,
                               const int* __restrict__ stride_p, float* ws,
                               unsigned long long ws_size, int n) {
    int stride = *stride_p;
    bool cls = use_class(stride, ws_size);
    int nc = num_classes(stride);
    float* buf  = ws;
    float* bins = (float*)((char*)ws + BINS_OFF_B);
    int gid = blockIdx.x * blockDim.x + threadIdx.x;
    if (gid >= n) return;
    int t = ticks[gid];
    int x = xs[gid];
    int y = ys[gid];
    float v = vals[gid];
    if (cls) {
        int cx = (x < KW - 1) ? x : (KW - 1) + (x - (KW - 1)) % stride;
        int cy = (y < KH - 1) ? y : (KH - 1) + (y - (KH - 1)) % stride;
        unsafeAtomicAdd(&bins[((long long)t * nc + cx) * nc + cy], v);
    } else {
        for (int ky = 0; ky < KH; ++ky) {
            int oy = y - ky;
            if (oy < 0 || (oy % stride) != 0) continue;
            for (int kx = 0; kx < KW; ++kx) {
                int ox = x - kx;
                if (ox < 0 || (ox % stride) != 0) continue;
                unsafeAtomicAdd(&buf[(ky * KW + kx) * TICKS + t], v);
            }
        }
    }
}

__global__ void combine_kernel(const int* __restrict__ stride_p, float* ws,
                               unsigned long long ws_size) {
    int stride = *stride_p;
    if (!use_class(stride, ws_size)) return;   // direct path already filled buf
    int nc = num_classes(stride);
    const float* bins = (const float*)((const char*)ws + BINS_OFF_B);
    int i = blockIdx.x * blockDim.x + threadIdx.x;
    if (i >= BUF_ELEMS) return;
    int tap = i / TICKS;
    int t   = i % TICKS;
    int ky = tap / KW, kx = tap % KW;
    float s = 0.0f;
    for (int cx = kx; cx < nc; cx += stride)
        for (int cy = ky; cy < nc; cy += stride)
            s += bins[((long long)t * nc + cx) * nc + cy];
    ws[tap * TICKS + t] = s;   // counts of 1.0f: exact, order-independent
}

// P[t][c] = sum_tap W[c,tap] * buf[tap, t-1]   (1-tick synaptic delay; P[0]=0)
// gid order: lanes share t -> buf reads broadcast (same addr), P stores coalesced.
__global__ void matmul_kernel(const float* __restrict__ W, float* ws) {
    int gid = blockIdx.x * blockDim.x + threadIdx.x;
    if (gid >= P_ELEMS) return;
    int t = gid / OUT_CH;
    int c = gid % OUT_CH;
    const float* buf = ws;
    float* P = (float*)((char*)ws + P_OFF_B);
    float acc = 0.0f;
    if (t > 0) {
        const float* wrow = W + c * NTAPS;
        const float* bcol = buf + (t - 1);
        #pragma unroll
        for (int tap = 0; tap < NTAPS; ++tap)
            acc += wrow[tap] * bcol[tap * TICKS];
    }
    P[t * OUT_CH + c] = acc;
}

// One block, thread c = neuron c.  Sequential 1000-tick Izhikevich recurrence.
//  - P staged through double-buffered LDS (40-tick chunks); next chunk's global
//    loads issue into regs at chunk top (T14 split), reg->LDS write at chunk end:
//    L2 latency hidden under ~1800cy of compute.
//  - Outputs staged in LDS, inner dim padded to 21 (gcd(21,32)=1 -> 2-way bank
//    alias, free; unpadded 20 would be 8-way) and flushed every 20 ticks with
//    coalesced stores.
// Static LDS = 40960 + 21504 = 62464 B (< 64KB).  Arithmetic order mirrors JAX.
#define CH     40
#define SUB    20
#define SOUTP  21
#define NCHUNK (TICKS / CH)                 // 25
#define NV4    (CH * OUT_CH / 4 / OUT_CH)   // 10 float4 per thread per chunk

__global__ void __launch_bounds__(OUT_CH) sim_kernel(const float* __restrict__ ws_c,
                                                     float* __restrict__ out) {
    __shared__ float pch[2][CH * OUT_CH];       // [2][40][128]
    __shared__ float sout[2][OUT_CH][SOUTP];    // [2][128][21] (20 used)
    const float* P = (const float*)((const char*)ws_c + P_OFF_B);
    const int c = threadIdx.x;
    const float DECAY = (float)(1.0 - 0.001 / 0.01);   // 1 - DT/TAU_FALL
    const float DTC   = (float)(0.001 / 150.0);        // DT / C
    float v = -75.0f, u = 0.0f, ssum = 0.0f;

    {   // prologue: stage chunk 0 (one-time reg round-trip)
        const float4* src = (const float4*)P;
        float4* dst = (float4*)pch[0];
        #pragma unroll
        for (int j = 0; j < NV4; ++j)
            dst[j * OUT_CH + c] = src[j * OUT_CH + c];
    }
    __syncthreads();

    for (int k = 0; k < NCHUNK; ++k) {
        const int cur = k & 1;
        // issue next chunk's loads NOW; they drain at the first flush barrier
        // (~900cy away) and land in LDS only at chunk end.
        float4 r[NV4];                       // compile-time indexed (stays in VGPRs)
        const bool pf = (k + 1 < NCHUNK);
        if (pf) {
            const float4* src = (const float4*)(P + (k + 1) * CH * OUT_CH);
            #pragma unroll
            for (int j = 0; j < NV4; ++j) r[j] = src[j * OUT_CH + c];
        }
        for (int s0 = 0; s0 < CH; s0 += SUB) {
            #pragma unroll
            for (int tt = 0; tt < SUB; ++tt) {
                float p = pch[cur][(s0 + tt) * OUT_CH + c];  // 2-way alias: free
                ssum = ssum * DECAY + p;                 // factorized synapse sum
                float I = 350.0f + ssum;                 // (I_BIAS + I_IN) + s.sum
                float q = 1.2f * (v - (-75.0f));
                q = q * (v - (-45.0f));
                v = v + (q - u + I) * DTC;
                u = u + 0.01f * (5.0f * (v - (-75.0f)) - u) * 0.001f;  // new v
                float spk;
                if (v >= 50.0f) { spk = 1.0f; v = -56.0f; u = u + 130.0f; }
                else            { spk = 0.0f; }
                sout[0][c][tt] = spk;                    // stride 21: conflict-free
                sout[1][c][tt] = v;
            }
            __syncthreads();
            const int tb = k * CH + s0;
            for (int i = c; i < OUT_CH * SUB; i += OUT_CH) {   // coalesced flush
                int cc = i / SUB, tt = i % SUB;
                out[cc * TICKS + tb + tt] = sout[0][cc][tt];
                out[OUT_CH * TICKS + cc * TICKS + tb + tt] = sout[1][cc][tt];
            }
            __syncthreads();
        }
        if (pf) {   // reg -> other LDS buffer; readers of pch[cur] are all past
            float4* dst = (float4*)pch[cur ^ 1];
            #pragma unroll
            for (int j = 0; j < NV4; ++j) dst[j * OUT_CH + c] = r[j];
        }
        __syncthreads();
    }
}

extern "C" void kernel_launch(void* const* d_in, const int* in_sizes, int n_in,
                              void* d_out, int out_size, void* d_ws, size_t ws_size,
                              hipStream_t stream) {
    const int*   ticks   = (const int*)d_in[0];
    const int*   xs      = (const int*)d_in[1];
    const int*   ys      = (const int*)d_in[2];
    const float* vals    = (const float*)d_in[3];
    const float* W       = (const float*)d_in[4];
    const int*   stridep = (const int*)d_in[5];
    float* ws  = (float*)d_ws;
    float* out = (float*)d_out;
    int n = in_sizes[0];
    unsigned long long wsz = (unsigned long long)ws_size;

    zero_kernel<<<1024, 256, 0, stream>>>(ws, stridep, wsz);
    scatter_kernel<<<(n + 255) / 256, 256, 0, stream>>>(ticks, xs, ys, vals,
                                                        stridep, ws, wsz, n);
    combine_kernel<<<(BUF_ELEMS + 255) / 256, 256, 0, stream>>>(stridep, ws, wsz);
    matmul_kernel<<<(P_ELEMS + 255) / 256, 256, 0, stream>>>(W, ws);
    sim_kernel<<<1, OUT_CH, 0, stream>>>(ws, out);
}

// Round 6
// 209.456 us; speedup vs baseline: 1.4370x; 1.4370x over previous
//
#include <hip/hip_runtime.h>
#include <cstdint>

#define TICKS   1000
#define KH      7
#define KW      7
#define NTAPS   49
#define OUT_CH  128

#define BUF_ELEMS   (NTAPS * TICKS)      // 49000 floats at ws[0]
#define P_OFF_B     196608               // byte offset of P^T[c*1000+t] (128000 floats)
#define P_ELEMS     (OUT_CH * TICKS)
#define BINS_OFF_B  708608               // byte offset of class bins

// x-classes: x<6 -> x exactly; x>=6 -> 6 + (x-6)%stride.  Validity of tap kx for
// class cx is (cx>=kx) && ((cx-kx)%stride==0) — exact for x<6; for x>=6, cx>=6>=kx
// always, and (x-kx) ≡ (cx-kx) (mod stride) since x ≡ cx (mod stride).
static __device__ __forceinline__ int num_classes(int stride) {
    int n = (KW - 1) + stride;
    return n > 128 ? 128 : n;
}

static __device__ __forceinline__ bool use_class(int stride, unsigned long long ws_size) {
    if (stride < 1) return false;
    long long nc = num_classes(stride);
    long long bytes = (long long)TICKS * nc * nc * 4;
    return (long long)BINS_OFF_B + bytes <= (long long)ws_size;
}

__global__ void zero_kernel(float* ws, const int* __restrict__ stride_p,
                            unsigned long long ws_size) {
    int stride = *stride_p;
    long long nbins = 0;
    if (use_class(stride, ws_size)) {
        long long nc = num_classes(stride);
        nbins = (long long)TICKS * nc * nc;
    }
    float* bins = (float*)((char*)ws + BINS_OFF_B);
    long long gid = (long long)blockIdx.x * blockDim.x + threadIdx.x;
    long long gsz = (long long)gridDim.x * blockDim.x;
    for (long long i = gid; i < BUF_ELEMS; i += gsz) ws[i] = 0.0f;
    for (long long i = gid; i < nbins; i += gsz) bins[i] = 0.0f;
}

__global__ void scatter_kernel(const int* __restrict__ ticks, const int* __restrict__ xs,
                               const int* __restrict__ ys, const float* __restrict__ vals,
                               const int* __restrict__ stride_p, float* ws,
                               unsigned long long ws_size, int n) {
    int stride = *stride_p;
    bool cls = use_class(stride, ws_size);
    int nc = num_classes(stride);
    float* buf  = ws;
    float* bins = (float*)((char*)ws + BINS_OFF_B);
    int gid = blockIdx.x * blockDim.x + threadIdx.x;
    if (gid >= n) return;
    int t = ticks[gid];
    int x = xs[gid];
    int y = ys[gid];
    float v = vals[gid];
    if (cls) {
        int cx = (x < KW - 1) ? x : (KW - 1) + (x - (KW - 1)) % stride;
        int cy = (y < KH - 1) ? y : (KH - 1) + (y - (KH - 1)) % stride;
        unsafeAtomicAdd(&bins[((long long)t * nc + cx) * nc + cy], v);
    } else {
        for (int ky = 0; ky < KH; ++ky) {
            int oy = y - ky;
            if (oy < 0 || (oy % stride) != 0) continue;
            for (int kx = 0; kx < KW; ++kx) {
                int ox = x - kx;
                if (ox < 0 || (ox % stride) != 0) continue;
                unsafeAtomicAdd(&buf[(ky * KW + kx) * TICKS + t], v);
            }
        }
    }
}

__global__ void combine_kernel(const int* __restrict__ stride_p, float* ws,
                               unsigned long long ws_size) {
    int stride = *stride_p;
    if (!use_class(stride, ws_size)) return;   // direct path already filled buf
    int nc = num_classes(stride);
    const float* bins = (const float*)((const char*)ws + BINS_OFF_B);
    int i = blockIdx.x * blockDim.x + threadIdx.x;
    if (i >= BUF_ELEMS) return;
    int tap = i / TICKS;
    int t   = i % TICKS;
    int ky = tap / KW, kx = tap % KW;
    float s = 0.0f;
    for (int cx = kx; cx < nc; cx += stride)
        for (int cy = ky; cy < nc; cy += stride)
            s += bins[((long long)t * nc + cx) * nc + cy];
    ws[tap * TICKS + t] = s;   // counts of 1.0f: exact, order-independent
}

// P^T[c][t] = sum_tap W[c,tap] * buf[tap, t-1]   (1-tick delay; P^T[c][0]=0)
// gid = c*TICKS + t: wave shares c -> W reads broadcast, buf reads coalesced
// (64 consecutive t), stores perfectly coalesced.  Tap order unchanged -> P
// values bit-identical to the r3-passing layout.
__global__ void matmul_kernel(const float* __restrict__ W, float* ws) {
    int gid = blockIdx.x * blockDim.x + threadIdx.x;
    if (gid >= P_ELEMS) return;
    int c = gid / TICKS;
    int t = gid - c * TICKS;
    const float* buf = ws;
    float* PT = (float*)((char*)ws + P_OFF_B);
    float acc = 0.0f;
    if (t > 0) {
        const float* wrow = W + c * NTAPS;
        const float* bcol = buf + (t - 1);
        #pragma unroll
        for (int tap = 0; tap < NTAPS; ++tap)
            acc += wrow[tap] * bcol[tap * TICKS];
    }
    PT[gid] = acc;
}

// One block, thread c = neuron c.  Fully register-resident: P column double-
// buffered in 2x25 float2 regs (prefetch one 50-tick chunk = ~2000cy ahead);
// outputs batched 4 ticks in regs -> one float4 store each, no LDS, no
// __syncthreads, so no forced vmcnt(0)/lgkmcnt(0) drains anywhere in the loop.
// PHASE = chunk_start % 4 (0 or 2) keeps all reg indexing compile-time.
// Per-tick arithmetic textually identical to the r3-passing version.
#define SCH 50
#define SC2 (SCH / 2)          // 25 float2 per chunk
#define NCH (TICKS / SCH)      // 20 chunks, processed in pairs

#define RUN_CHUNK(BUF, T0, PHASE)                                         \
    _Pragma("unroll")                                                     \
    for (int tt = 0; tt < SCH; ++tt) {                                    \
        float p = ((tt & 1) ? BUF[tt >> 1].y : BUF[tt >> 1].x);           \
        ssum = ssum * DECAY + p;                                          \
        float I = 350.0f + ssum;                                          \
        float q = 1.2f * (v - (-75.0f));                                  \
        q = q * (v - (-45.0f));                                           \
        v = v + (q - u + I) * DTC;                                        \
        u = u + 0.01f * (5.0f * (v - (-75.0f)) - u) * 0.001f;             \
        float spk;                                                        \
        if (v >= 50.0f) { spk = 1.0f; v = -56.0f; u = u + 130.0f; }       \
        else            { spk = 0.0f; }                                   \
        o_s[(tt + PHASE) & 3] = spk;                                      \
        o_v[(tt + PHASE) & 3] = v;                                        \
        if (((tt + PHASE) & 3) == 3) {                                    \
            const int tb = (T0) + tt - 3;  /* tb % 4 == 0: aligned */     \
            *(float4*)(out + (size_t)c * TICKS + tb) =                    \
                make_float4(o_s[0], o_s[1], o_s[2], o_s[3]);              \
            *(float4*)(out + (size_t)(OUT_CH * TICKS) + (size_t)c * TICKS + tb) = \
                make_float4(o_v[0], o_v[1], o_v[2], o_v[3]);              \
        }                                                                 \
    }

__global__ void __launch_bounds__(OUT_CH) sim_kernel(const float* __restrict__ ws_c,
                                                     float* __restrict__ out) {
    const float2* PT2 = (const float2*)((const char*)ws_c + P_OFF_B);
    const int c = threadIdx.x;
    const float DECAY = (float)(1.0 - 0.001 / 0.01);   // 1 - DT/TAU_FALL
    const float DTC   = (float)(0.001 / 150.0);        // DT / C
    float v = -75.0f, u = 0.0f, ssum = 0.0f;
    float o_s[4], o_v[4];
    float2 bA[SC2], bB[SC2];
    const float2* base = PT2 + (size_t)c * (TICKS / 2);

    #pragma unroll
    for (int j = 0; j < SC2; ++j) bA[j] = base[j];          // chunk 0

    for (int kk = 0; kk < NCH / 2; ++kk) {
        const int t0 = kk * 2 * SCH;                        // t0 % 4 == 0
        {   // prefetch odd chunk (consumed ~2000cy later)
            const float2* s = base + (t0 + SCH) / 2;
            #pragma unroll
            for (int j = 0; j < SC2; ++j) bB[j] = s[j];
        }
        RUN_CHUNK(bA, t0, 0)
        if (kk + 1 < NCH / 2) {                             // prefetch next even
            const float2* s = base + (t0 + 2 * SCH) / 2;
            #pragma unroll
            for (int j = 0; j < SC2; ++j) bA[j] = s[j];
        }
        RUN_CHUNK(bB, t0 + SCH, 2)                          // (t0+50) % 4 == 2
    }
    // chunk pairing: A-chunks end with ticks 48,49 pending in o_s[0..1]; the
    // following B-chunk (PHASE=2) flushes them at its tt==1 (tb%4==0).  B-chunks
    // end self-flushed (tt=49 -> idx 3), so tick 999 is stored.
}

extern "C" void kernel_launch(void* const* d_in, const int* in_sizes, int n_in,
                              void* d_out, int out_size, void* d_ws, size_t ws_size,
                              hipStream_t stream) {
    const int*   ticks   = (const int*)d_in[0];
    const int*   xs      = (const int*)d_in[1];
    const int*   ys      = (const int*)d_in[2];
    const float* vals    = (const float*)d_in[3];
    const float* W       = (const float*)d_in[4];
    const int*   stridep = (const int*)d_in[5];
    float* ws  = (float*)d_ws;
    float* out = (float*)d_out;
    int n = in_sizes[0];
    unsigned long long wsz = (unsigned long long)ws_size;

    zero_kernel<<<1024, 256, 0, stream>>>(ws, stridep, wsz);
    scatter_kernel<<<(n + 255) / 256, 256, 0, stream>>>(ticks, xs, ys, vals,
                                                        stridep, ws, wsz, n);
    combine_kernel<<<(BUF_ELEMS + 255) / 256, 256, 0, stream>>>(stridep, ws, wsz);
    matmul_kernel<<<(P_ELEMS + 255) / 256, 256, 0, stream>>>(W, ws);
    sim_kernel<<<1, OUT_CH, 0, stream>>>(ws, out);
}